// Round 2
// baseline (1339.100 us; speedup 1.0000x reference)
//
#include <hip/hip_runtime.h>
#include <math.h>

#define Lc 4
#define Bc 4
#define Tc 1024
#define TCc 1024
#define T1c 2048
#define Dc 384
#define DKc 256
#define FFc 1536
#define TTc 0.1f
#define EPSc 1e-5f

typedef unsigned short u16;
typedef __attribute__((ext_vector_type(8))) __bf16 bf16x8;
typedef __attribute__((ext_vector_type(4))) float f32x4;

__device__ inline u16 f2bf(float f) {
  union { float f; unsigned u; } x; x.f = f;
  unsigned r = x.u + 0x7fffu + ((x.u >> 16) & 1u);
  return (u16)(r >> 16);
}

// ---------------- elementwise fp32 -> bf16 ----------------
__global__ void cvt_bf16(const float* __restrict__ in, u16* __restrict__ out, long n) {
  long i = (long)blockIdx.x * 256 + threadIdx.x;
  long st = (long)gridDim.x * 256;
  for (; i < n; i += st) out[i] = f2bf(in[i]);
}

__global__ void zero_f32(float* __restrict__ p, long n) {
  long i = (long)blockIdx.x * 256 + threadIdx.x;
  long st = (long)gridDim.x * 256;
  for (; i < n; i += st) p[i] = 0.0f;
}

// concat per-layer biases: o[l*768+t] = t<384 ? a[l*384+t] : b[l*384+t-384]
__global__ void concat_bias(const float* __restrict__ a, const float* __restrict__ b,
                            float* __restrict__ o) {
  int l = blockIdx.x, t = threadIdx.x;
  o[l * 768 + t] = (t < Dc) ? a[l * Dc + t] : b[l * Dc + t - Dc];
}

// ------- score_c[z] (TC,T1) fp32 -> scT[z] (T1,TC) bf16, z over L*B -------
__global__ __launch_bounds__(256) void transpose_cvt(const float* __restrict__ src,
                                                     u16* __restrict__ dst) {
  __shared__ float tile[32][33];
  const int z = blockIdx.z;
  const float* s = src + (long)z * TCc * T1c;
  u16* d = dst + (long)z * T1c * TCc;
  const int s0 = blockIdx.x * 32, c0 = blockIdx.y * 32;
  const int tx = threadIdx.x & 31, ty = threadIdx.x >> 5;
#pragma unroll
  for (int j = 0; j < 4; ++j)
    tile[ty + j * 8][tx] = s[(long)(c0 + ty + j * 8) * T1c + s0 + tx];
  __syncthreads();
#pragma unroll
  for (int j = 0; j < 4; ++j)
    d[(long)(s0 + ty + j * 8) * TCc + c0 + tx] = f2bf(tile[tx][ty + j * 8]);
}

// ---------------- generic bf16 GEMM: C = alpha*(A.B^T) + bias ----------------
// A: (M,K) bf16 rows at stride lda, B: (N,K) bf16 rows at stride ldb.
// Grid: (N/128, M/128, batch*ksplit).  BIAS_MODE: 0 none, 1 per-col, 2 per-row.
// OUT_MODE: 0 f32 store, 1 bf16 store, 2 f32 atomicAdd (split-K).
template<int BIAS_MODE, int RELU, int OUT_MODE>
__global__ __launch_bounds__(256) void gemm_bt(
    const u16* __restrict__ A, const u16* __restrict__ B,
    void* __restrict__ C, const float* __restrict__ bias,
    float alpha, int N, int K, int lda, int ldb,
    long sA, long sB, long sC, long sBias, int ksplit)
{
  __shared__ __attribute__((aligned(16))) u16 As[128 * 32];
  __shared__ __attribute__((aligned(16))) u16 Bs[128 * 32];
  const int bz = blockIdx.z;
  const int b = bz / ksplit;
  const int kc = bz - b * ksplit;
  const int Klen = K / ksplit;
  const int k0 = kc * Klen;
  const u16* Ab = A + (long)b * sA;
  const u16* Bb = B + (long)b * sB;
  const float* biasb = bias + (long)b * sBias;
  const long tm = (long)blockIdx.y * 128;
  const long tn = (long)blockIdx.x * 128;
  const int tid = threadIdx.x;
  const int lane = tid & 63, wv = tid >> 6;
  const int wm = (wv >> 1) * 64, wn = (wv & 1) * 64;
  const int q = lane >> 4, r = lane & 15;
  const int ldr = lane >> 2;        // row within 16-row group
  const int ldc = (lane & 3) * 8;   // ushort offset within row (16B per lane)

  const f32x4 zero4 = {0.0f, 0.0f, 0.0f, 0.0f};
  f32x4 acc[4][4];
#pragma unroll
  for (int i = 0; i < 4; ++i)
#pragma unroll
    for (int j = 0; j < 4; ++j) acc[i][j] = zero4;

  for (int kt = k0; kt < k0 + Klen; kt += 32) {
#pragma unroll
    for (int j = 0; j < 2; ++j) {
      const int rowo = wv * 32 + j * 16;
      const u16* ga = Ab + (tm + rowo + ldr) * (long)lda + kt + ldc;
      __builtin_amdgcn_global_load_lds(
          (const __attribute__((address_space(1))) void*)ga,
          (__attribute__((address_space(3))) void*)(As + rowo * 32), 16, 0, 0);
      const u16* gb = Bb + (tn + rowo + ldr) * (long)ldb + kt + ldc;
      __builtin_amdgcn_global_load_lds(
          (const __attribute__((address_space(1))) void*)gb,
          (__attribute__((address_space(3))) void*)(Bs + rowo * 32), 16, 0, 0);
    }
    __syncthreads();

    bf16x8 af[4], bfr[4];
#pragma unroll
    for (int i = 0; i < 4; ++i) {
      af[i]  = *(const bf16x8*)(As + (wm + i * 16 + r) * 32 + q * 8);
      bfr[i] = *(const bf16x8*)(Bs + (wn + i * 16 + r) * 32 + q * 8);
    }
#pragma unroll
    for (int i = 0; i < 4; ++i)
#pragma unroll
      for (int j = 0; j < 4; ++j)
        acc[i][j] = __builtin_amdgcn_mfma_f32_16x16x32_bf16(af[i], bfr[j], acc[i][j], 0, 0, 0);
    __syncthreads();
  }

  // epilogue: D layout col=lane&15, row=(lane>>4)*4+reg  [measured m89/m91]
#pragma unroll
  for (int i = 0; i < 4; ++i)
#pragma unroll
    for (int j = 0; j < 4; ++j)
#pragma unroll
      for (int v = 0; v < 4; ++v) {
        long row = tm + wm + i * 16 + q * 4 + v;
        long col = tn + wn + j * 16 + r;
        float val = acc[i][j][v] * alpha;
        if (BIAS_MODE == 1 && kc == 0) val += biasb[col];
        if (BIAS_MODE == 2 && kc == 0) val += biasb[row];
        if (RELU) val = fmaxf(val, 0.0f);
        long idx = (long)b * sC + row * (long)N + col;
        if (OUT_MODE == 0)      ((float*)C)[idx] = val;
        else if (OUT_MODE == 1) ((u16*)C)[idx] = f2bf(val);
        else                    atomicAdd((float*)C + idx, val);
      }
}

// -------- blended = TT*softmax(mixed) + (1-TT)*softmax(att), rows of T1 --------
__global__ __launch_bounds__(256) void blend_softmax(
    const float* __restrict__ att, const float* __restrict__ mixed,
    u16* __restrict__ out)
{
  const long row = blockIdx.x;
  const int tid = threadIdx.x;
  const float* ar = att + row * T1c;
  const float* mr = mixed + row * T1c;
  float a[8], m[8];
#pragma unroll
  for (int i = 0; i < 8; ++i) { a[i] = ar[tid + i * 256]; m[i] = mr[tid + i * 256]; }
  float amax = a[0], mmax = m[0];
#pragma unroll
  for (int i = 1; i < 8; ++i) { amax = fmaxf(amax, a[i]); mmax = fmaxf(mmax, m[i]); }
#pragma unroll
  for (int off = 32; off > 0; off >>= 1) {
    amax = fmaxf(amax, __shfl_xor(amax, off));
    mmax = fmaxf(mmax, __shfl_xor(mmax, off));
  }
  __shared__ float red[8];
  const int lane = tid & 63, wv = tid >> 6;
  if (lane == 0) { red[wv] = amax; red[4 + wv] = mmax; }
  __syncthreads();
  amax = fmaxf(fmaxf(red[0], red[1]), fmaxf(red[2], red[3]));
  mmax = fmaxf(fmaxf(red[4], red[5]), fmaxf(red[6], red[7]));
  __syncthreads();
  float asum = 0.f, msum = 0.f;
#pragma unroll
  for (int i = 0; i < 8; ++i) {
    a[i] = __expf(a[i] - amax); asum += a[i];
    m[i] = __expf(m[i] - mmax); msum += m[i];
  }
#pragma unroll
  for (int off = 32; off > 0; off >>= 1) {
    asum += __shfl_xor(asum, off);
    msum += __shfl_xor(msum, off);
  }
  if (lane == 0) { red[wv] = asum; red[4 + wv] = msum; }
  __syncthreads();
  asum = red[0] + red[1] + red[2] + red[3];
  msum = red[4] + red[5] + red[6] + red[7];
  const float ca = (1.0f - TTc) / asum, cm = TTc / msum;
#pragma unroll
  for (int i = 0; i < 8; ++i)
    out[row * T1c + tid + i * 256] = f2bf(a[i] * ca + m[i] * cm);
}

// -------- x = LN(xin + z) ; writes fp32 x and bf16 x --------
__global__ __launch_bounds__(384) void add_ln(
    const float* __restrict__ xin, const float* __restrict__ z,
    const float* __restrict__ g, const float* __restrict__ be,
    float* __restrict__ xout, u16* __restrict__ xbf)
{
  const long row = blockIdx.x;
  const int d = threadIdx.x;
  float v = xin[row * Dc + d] + z[row * Dc + d];
  float s = v, s2 = v * v;
#pragma unroll
  for (int off = 32; off > 0; off >>= 1) {
    s  += __shfl_xor(s, off);
    s2 += __shfl_xor(s2, off);
  }
  __shared__ float red[12];
  const int lane = d & 63, wv = d >> 6;
  if (lane == 0) { red[wv] = s; red[6 + wv] = s2; }
  __syncthreads();
  float S = 0.f, S2 = 0.f;
#pragma unroll
  for (int w = 0; w < 6; ++w) { S += red[w]; S2 += red[6 + w]; }
  const float mean = S * (1.0f / Dc);
  const float var  = S2 * (1.0f / Dc) - mean * mean;
  const float rstd = rsqrtf(var + EPSc);
  const float y = (v - mean) * rstd * g[d] + be[d];
  xout[row * Dc + d] = y;
  xbf[row * Dc + d] = f2bf(y);
}

extern "C" void kernel_launch(void* const* d_in, const int* in_sizes, int n_in,
                              void* d_out, int out_size, void* d_ws, size_t ws_size,
                              hipStream_t stream)
{
  const float* tgt     = (const float*)d_in[0];
  const float* memory  = (const float*)d_in[1];
  const float* score_c = (const float*)d_in[2];
  const float* out_c   = (const float*)d_in[3];
  const float* Wq  = (const float*)d_in[4];  const float* bq  = (const float*)d_in[5];
  const float* Wk  = (const float*)d_in[6];  const float* bk  = (const float*)d_in[7];
  const float* Wv  = (const float*)d_in[8];  const float* bv  = (const float*)d_in[9];
  const float* Wkn = (const float*)d_in[10]; const float* bkn = (const float*)d_in[11];
  const float* Wun = (const float*)d_in[12]; const float* bun = (const float*)d_in[13];
  const float* W1  = (const float*)d_in[14]; const float* b1  = (const float*)d_in[15];
  const float* W2  = (const float*)d_in[16]; const float* b2  = (const float*)d_in[17];
  const float* g1  = (const float*)d_in[18]; const float* be1 = (const float*)d_in[19];
  const float* g2  = (const float*)d_in[20]; const float* be2 = (const float*)d_in[21];
  (void)in_sizes; (void)n_in; (void)out_size;

  char* p = (char*)d_ws;
  auto alloc = [&](size_t b) { char* r = p; p += (b + 255) & ~(size_t)255; return r; };

  u16* wk_bf   = (u16*)alloc((size_t)Lc * Dc * DKc * 2);
  u16* wv_bf   = (u16*)alloc((size_t)Lc * Dc * DKc * 2);
  u16* wkn_bf  = (u16*)alloc((size_t)Lc * Dc * Dc * 2);
  u16* w1_bf   = (u16*)alloc((size_t)Lc * FFc * Dc * 2);
  u16* w2_bf   = (u16*)alloc((size_t)Lc * Dc * FFc * 2);
  u16* wqu_bf  = (u16*)alloc((size_t)Lc * 2 * Dc * Dc * 2);  // [l][768][384]
  float* bqu   = (float*)alloc((size_t)Lc * 2 * Dc * 4);
  u16* mem_bf  = (u16*)alloc((size_t)Bc * T1c * DKc * 2);
  u16* outc_bf = (u16*)alloc((size_t)Lc * Bc * TCc * Dc * 2);
  u16* x_bf    = (u16*)alloc((size_t)Bc * Tc * Dc * 2);
  float* xbuf  = (float*)alloc((size_t)Bc * Tc * Dc * 4);
  u16* qunk_bf = (u16*)alloc((size_t)Bc * Tc * 2 * Dc * 2);  // [B*T][768]
  u16* k_all   = (u16*)alloc((size_t)Bc * T1c * Lc * Dc * 2); // [B*T1][1536]
  u16* vT_all  = (u16*)alloc((size_t)Bc * Lc * Dc * T1c * 2); // [b][1536][2048]
  u16* kno_all = (u16*)alloc((size_t)Lc * Bc * TCc * Dc * 2); // [l][B*TC][384]
  u16* s1_bf   = (u16*)alloc((size_t)Bc * Tc * TCc * 2);
  u16* scT_all = (u16*)alloc((size_t)Lc * Bc * T1c * TCc * 2);
  float* att   = (float*)alloc((size_t)Bc * Tc * T1c * 4);
  float* mixed = (float*)alloc((size_t)Bc * Tc * T1c * 4);
  u16* blended = (u16*)alloc((size_t)Bc * Tc * T1c * 2);
  float* zbuf  = (float*)alloc((size_t)Bc * Tc * Dc * 4);
  float* y2buf = (float*)alloc((size_t)Bc * Tc * Dc * 4);
  u16* h_bf    = (u16*)alloc((size_t)Bc * Tc * FFc * 2);

  if ((size_t)(p - (char*)d_ws) > ws_size) return;  // fail loudly (poisoned out)

  auto cvt = [&](const float* s, u16* d, long n) {
    int blocks = (int)((n + 255) / 256); if (blocks > 4096) blocks = 4096;
    cvt_bf16<<<blocks, 256, 0, stream>>>(s, d, n);
  };
  cvt(Wk,  wk_bf,  (long)Lc * Dc * DKc);
  cvt(Wv,  wv_bf,  (long)Lc * Dc * DKc);
  cvt(Wkn, wkn_bf, (long)Lc * Dc * Dc);
  cvt(W1,  w1_bf,  (long)Lc * FFc * Dc);
  cvt(W2,  w2_bf,  (long)Lc * Dc * FFc);
  cvt(memory, mem_bf, (long)Bc * T1c * DKc);
  cvt(out_c, outc_bf, (long)Lc * Bc * TCc * Dc);
  cvt(tgt, x_bf, (long)Bc * Tc * Dc);
  for (int l = 0; l < Lc; ++l) {  // wqu = [Wq[l]; Wun[l]] rows
    cvt(Wq + (long)l * Dc * Dc,  wqu_bf + (long)l * 2 * Dc * Dc, (long)Dc * Dc);
    cvt(Wun + (long)l * Dc * Dc, wqu_bf + (long)l * 2 * Dc * Dc + Dc * Dc, (long)Dc * Dc);
  }
  concat_bias<<<Lc, 2 * Dc, 0, stream>>>(bq, bun, bqu);

  // scT_all: all L*B score_c panels transposed at once
  transpose_cvt<<<dim3(T1c / 32, TCc / 32, Lc * Bc), 256, 0, stream>>>(score_c, scT_all);

  // k_all = memory . Wk_allT + bk_flat   (8192 x 1536, K=256) — all layers
  gemm_bt<1,0,1><<<dim3(Lc*Dc/128, Bc*T1c/128, 1), 256, 0, stream>>>(
      mem_bf, wk_bf, k_all, bk, 1.0f, Lc*Dc, DKc, DKc, DKc, 0, 0, 0, 0, 1);
  // vT_all[b] = Wv_all . memory[b]^T + bv(row)   (1536 x 2048, K=256), batch B
  gemm_bt<2,0,1><<<dim3(T1c/128, Lc*Dc/128, Bc), 256, 0, stream>>>(
      wv_bf, mem_bf, vT_all, bv, 1.0f, T1c, DKc, DKc, DKc,
      0, (long)T1c*DKc, (long)Lc*Dc*T1c, 0, 1);
  // kno_all[l] = out_c[l] . Wkn[l]^T + bkn[l]   (4096 x 384, K=384), batch L
  gemm_bt<1,0,1><<<dim3(Dc/128, Bc*TCc/128, Lc), 256, 0, stream>>>(
      outc_bf, wkn_bf, kno_all, bkn, 1.0f, Dc, Dc, Dc, Dc,
      (long)Bc*TCc*Dc, (long)Dc*Dc, (long)Bc*TCc*Dc, Dc, 1);

  const float scale = 1.0f / sqrtf((float)Dc);

  for (int l = 0; l < Lc; ++l) {
    // qunk = x . [Wq;Wun]^T + [bq;bun]   (4096 x 768, K=384)
    gemm_bt<1,0,1><<<dim3(2*Dc/128, Bc*Tc/128, 1), 256, 0, stream>>>(
        x_bf, wqu_bf + (long)l*2*Dc*Dc, qunk_bf, bqu + l*2*Dc,
        1.0f, 2*Dc, Dc, Dc, Dc, 0, 0, 0, 0, 1);
    // att[b] = scale * q[b] . k[b]^T   (1024 x 2048, K=384)
    gemm_bt<0,0,0><<<dim3(T1c/128, Tc/128, Bc), 256, 0, stream>>>(
        qunk_bf, k_all + l*Dc, att, nullptr, scale, T1c, Dc, 2*Dc, Lc*Dc,
        (long)Tc*2*Dc, (long)T1c*Lc*Dc, (long)Tc*T1c, 0, 1);
    // score1[b] = scale * unk[b] . kno[l][b]^T   (1024 x 1024, K=384) bf16
    gemm_bt<0,0,1><<<dim3(TCc/128, Tc/128, Bc), 256, 0, stream>>>(
        qunk_bf + Dc, kno_all + (long)l*Bc*TCc*Dc, s1_bf, nullptr, scale,
        TCc, Dc, 2*Dc, Dc, (long)Tc*2*Dc, (long)TCc*Dc, (long)Tc*TCc, 0, 1);
    // mixed[b] = score1[b] . scT[l][b]^T   (1024 x 2048, K=1024)
    gemm_bt<0,0,0><<<dim3(T1c/128, Tc/128, Bc), 256, 0, stream>>>(
        s1_bf, scT_all + (long)l*Bc*T1c*TCc, mixed, nullptr, 1.0f,
        T1c, TCc, TCc, TCc, (long)Tc*TCc, (long)T1c*TCc, (long)Tc*T1c, 0, 1);
    // blended = TT*softmax(mixed) + (1-TT)*softmax(att)
    blend_softmax<<<Bc*Tc, 256, 0, stream>>>(att, mixed, blended);
    // z[b] = blended[b] . vT[l][b]^T   (1024 x 384, K=2048), split-K=4
    zero_f32<<<1536, 256, 0, stream>>>(zbuf, (long)Bc*Tc*Dc);
    gemm_bt<0,0,2><<<dim3(Dc/128, Tc/128, Bc*4), 256, 0, stream>>>(
        blended, vT_all + (long)l*Dc*T1c, zbuf, nullptr, 1.0f,
        Dc, T1c, T1c, T1c, (long)Tc*T1c, (long)Lc*Dc*T1c, (long)Tc*Dc, 0, 4);
    // x = LN(x + z)
    add_ln<<<Bc*Tc, Dc, 0, stream>>>(
        (l == 0) ? tgt : xbuf, zbuf, g1 + l*Dc, be1 + l*Dc, xbuf, x_bf);
    // h = relu(x . W1^T + b1)   (4096 x 1536, K=384) bf16
    gemm_bt<1,1,1><<<dim3(FFc/128, Bc*Tc/128, 1), 256, 0, stream>>>(
        x_bf, w1_bf + (long)l*FFc*Dc, h_bf, b1 + l*FFc, 1.0f,
        FFc, Dc, Dc, Dc, 0, 0, 0, 0, 1);
    // y2 = h . W2^T + b2   (4096 x 384, K=1536), split-K=4
    zero_f32<<<1536, 256, 0, stream>>>(y2buf, (long)Bc*Tc*Dc);
    gemm_bt<1,0,2><<<dim3(Dc/128, Bc*Tc/128, 4), 256, 0, stream>>>(
        h_bf, w2_bf + (long)l*Dc*FFc, y2buf, b2 + l*Dc, 1.0f,
        Dc, FFc, FFc, FFc, 0, 0, 0, 0, 4);
    // x = LN(x + y2) ; last layer writes d_out
    add_ln<<<Bc*Tc, Dc, 0, stream>>>(
        xbuf, y2buf, g2 + l*Dc, be2 + l*Dc,
        (l == Lc - 1) ? (float*)d_out : xbuf, x_bf);
  }
}

// Round 3
// 1153.497 us; speedup vs baseline: 1.1609x; 1.1609x over previous
//
#include <hip/hip_runtime.h>
#include <math.h>

#define Lc 4
#define Bc 4
#define Tc 1024
#define TCc 1024
#define T1c 2048
#define Dc 384
#define DKc 256
#define FFc 1536
#define TTc 0.1f
#define EPSc 1e-5f

typedef unsigned short u16;
typedef __attribute__((ext_vector_type(8))) __bf16 bf16x8;
typedef __attribute__((ext_vector_type(4))) float f32x4;

__device__ inline u16 f2bf(float f) {
  union { float f; unsigned u; } x; x.f = f;
  unsigned r = x.u + 0x7fffu + ((x.u >> 16) & 1u);
  return (u16)(r >> 16);
}

// ---------------- elementwise fp32 -> bf16 ----------------
__global__ void cvt_bf16(const float* __restrict__ in, u16* __restrict__ out, long n) {
  long i = (long)blockIdx.x * 256 + threadIdx.x;
  long st = (long)gridDim.x * 256;
  for (; i < n; i += st) out[i] = f2bf(in[i]);
}

// concat per-layer biases: o[l*768+t] = t<384 ? a[l*384+t] : b[l*384+t-384]
__global__ void concat_bias(const float* __restrict__ a, const float* __restrict__ b,
                            float* __restrict__ o) {
  int l = blockIdx.x, t = threadIdx.x;
  o[l * 768 + t] = (t < Dc) ? a[l * Dc + t] : b[l * Dc + t - Dc];
}

// ------- score_c[z] (TC,T1) fp32 -> scT[z] (T1,TC) bf16, z over L*B -------
__global__ __launch_bounds__(256) void transpose_cvt(const float* __restrict__ src,
                                                     u16* __restrict__ dst) {
  __shared__ float tile[32][33];
  const int z = blockIdx.z;
  const float* s = src + (long)z * TCc * T1c;
  u16* d = dst + (long)z * T1c * TCc;
  const int s0 = blockIdx.x * 32, c0 = blockIdx.y * 32;
  const int tx = threadIdx.x & 31, ty = threadIdx.x >> 5;
#pragma unroll
  for (int j = 0; j < 4; ++j)
    tile[ty + j * 8][tx] = s[(long)(c0 + ty + j * 8) * T1c + s0 + tx];
  __syncthreads();
#pragma unroll
  for (int j = 0; j < 4; ++j)
    d[(long)(s0 + ty + j * 8) * TCc + c0 + tx] = f2bf(tile[tx][ty + j * 8]);
}

// ---------------- generic bf16 GEMM: C = alpha*(A.B^T) + bias ----------------
// A: (M,K) bf16 rows at stride lda, B: (N,K) bf16 rows at stride ldb.
// Grid: (N/128, M/128, batch*ksplit).  BIAS_MODE: 0 none, 1 per-col, 2 per-row.
// OUT_MODE: 0 f32 store (slab at kc*sSlab), 1 bf16 store, 3 f16 store.
// SWIZ: XCD-aware remap for 16x8 grids (mixed GEMM): co-resident blocks on one
// XCD share 2 n-tiles -> B working set 2.5MB < 4MB L2.
template<int BIAS_MODE, int RELU, int OUT_MODE, int SWIZ>
__global__ __launch_bounds__(256) void gemm_bt(
    const u16* __restrict__ A, const u16* __restrict__ B,
    void* __restrict__ C, const float* __restrict__ bias,
    float alpha, int N, int K, int lda, int ldb,
    long sA, long sB, long sC, long sBias, int ksplit, long sSlab)
{
  __shared__ __attribute__((aligned(16))) u16 As[128 * 32];
  __shared__ __attribute__((aligned(16))) u16 Bs[128 * 32];
  const int bz = blockIdx.z;
  const int b = bz / ksplit;
  const int kc = bz - b * ksplit;
  const int Klen = K / ksplit;
  const int k0 = kc * Klen;
  const u16* Ab = A + (long)b * sA;
  const u16* Bb = B + (long)b * sB;
  const float* biasb = bias + (long)b * sBias;
  long tm, tn;
  if (SWIZ) {  // grid must be (16, 8, z): id in [0,128)
    const int id = blockIdx.y * 16 + blockIdx.x;
    const int n_t = 2 * (id & 7) + ((id >> 3) & 1);
    const int m_t = id >> 4;
    tm = (long)m_t * 128; tn = (long)n_t * 128;
  } else {
    tm = (long)blockIdx.y * 128; tn = (long)blockIdx.x * 128;
  }
  const int tid = threadIdx.x;
  const int lane = tid & 63, wv = tid >> 6;
  const int wm = (wv >> 1) * 64, wn = (wv & 1) * 64;
  const int q = lane >> 4, r = lane & 15;
  const int ldr = lane >> 2;        // row within 16-row group
  const int ldc = (lane & 3) * 8;   // ushort offset within row (16B per lane)

  const f32x4 zero4 = {0.0f, 0.0f, 0.0f, 0.0f};
  f32x4 acc[4][4];
#pragma unroll
  for (int i = 0; i < 4; ++i)
#pragma unroll
    for (int j = 0; j < 4; ++j) acc[i][j] = zero4;

  for (int kt = k0; kt < k0 + Klen; kt += 32) {
#pragma unroll
    for (int j = 0; j < 2; ++j) {
      const int rowo = wv * 32 + j * 16;
      const u16* ga = Ab + (tm + rowo + ldr) * (long)lda + kt + ldc;
      __builtin_amdgcn_global_load_lds(
          (const __attribute__((address_space(1))) void*)ga,
          (__attribute__((address_space(3))) void*)(As + rowo * 32), 16, 0, 0);
      const u16* gb = Bb + (tn + rowo + ldr) * (long)ldb + kt + ldc;
      __builtin_amdgcn_global_load_lds(
          (const __attribute__((address_space(1))) void*)gb,
          (__attribute__((address_space(3))) void*)(Bs + rowo * 32), 16, 0, 0);
    }
    __syncthreads();

    bf16x8 af[4], bfr[4];
#pragma unroll
    for (int i = 0; i < 4; ++i) {
      af[i]  = *(const bf16x8*)(As + (wm + i * 16 + r) * 32 + q * 8);
      bfr[i] = *(const bf16x8*)(Bs + (wn + i * 16 + r) * 32 + q * 8);
    }
#pragma unroll
    for (int i = 0; i < 4; ++i)
#pragma unroll
      for (int j = 0; j < 4; ++j)
        acc[i][j] = __builtin_amdgcn_mfma_f32_16x16x32_bf16(af[i], bfr[j], acc[i][j], 0, 0, 0);
    __syncthreads();
  }

  // epilogue: D layout col=lane&15, row=(lane>>4)*4+reg  [measured m89/m91]
#pragma unroll
  for (int i = 0; i < 4; ++i)
#pragma unroll
    for (int j = 0; j < 4; ++j)
#pragma unroll
      for (int v = 0; v < 4; ++v) {
        long row = tm + wm + i * 16 + q * 4 + v;
        long col = tn + wn + j * 16 + r;
        float val = acc[i][j][v] * alpha;
        if (BIAS_MODE == 1 && kc == 0) val += biasb[col];
        if (BIAS_MODE == 2 && kc == 0) val += biasb[row];
        if (RELU) val = fmaxf(val, 0.0f);
        long idx = (long)kc * sSlab + (long)b * sC + row * (long)N + col;
        if (OUT_MODE == 0)      ((float*)C)[idx] = val;
        else if (OUT_MODE == 1) ((u16*)C)[idx] = f2bf(val);
        else                    ((_Float16*)C)[idx] = (_Float16)val;
      }
}

// -------- blended = TT*softmax(mixed) + (1-TT)*softmax(att), rows of T1 --------
__global__ __launch_bounds__(256) void blend_softmax(
    const _Float16* __restrict__ att, const _Float16* __restrict__ mixed,
    u16* __restrict__ out)
{
  const long row = blockIdx.x;
  const int tid = threadIdx.x;
  const _Float16* ar = att + row * T1c;
  const _Float16* mr = mixed + row * T1c;
  float a[8], m[8];
#pragma unroll
  for (int i = 0; i < 8; ++i) {
    a[i] = (float)ar[tid + i * 256];
    m[i] = (float)mr[tid + i * 256];
  }
  float amax = a[0], mmax = m[0];
#pragma unroll
  for (int i = 1; i < 8; ++i) { amax = fmaxf(amax, a[i]); mmax = fmaxf(mmax, m[i]); }
#pragma unroll
  for (int off = 32; off > 0; off >>= 1) {
    amax = fmaxf(amax, __shfl_xor(amax, off));
    mmax = fmaxf(mmax, __shfl_xor(mmax, off));
  }
  __shared__ float red[8];
  const int lane = tid & 63, wv = tid >> 6;
  if (lane == 0) { red[wv] = amax; red[4 + wv] = mmax; }
  __syncthreads();
  amax = fmaxf(fmaxf(red[0], red[1]), fmaxf(red[2], red[3]));
  mmax = fmaxf(fmaxf(red[4], red[5]), fmaxf(red[6], red[7]));
  __syncthreads();
  float asum = 0.f, msum = 0.f;
#pragma unroll
  for (int i = 0; i < 8; ++i) {
    a[i] = __expf(a[i] - amax); asum += a[i];
    m[i] = __expf(m[i] - mmax); msum += m[i];
  }
#pragma unroll
  for (int off = 32; off > 0; off >>= 1) {
    asum += __shfl_xor(asum, off);
    msum += __shfl_xor(msum, off);
  }
  if (lane == 0) { red[wv] = asum; red[4 + wv] = msum; }
  __syncthreads();
  asum = red[0] + red[1] + red[2] + red[3];
  msum = red[4] + red[5] + red[6] + red[7];
  const float ca = (1.0f - TTc) / asum, cm = TTc / msum;
#pragma unroll
  for (int i = 0; i < 8; ++i)
    out[row * T1c + tid + i * 256] = f2bf(a[i] * ca + m[i] * cm);
}

// -------- x = LN(xin + sum of 4 split-K slabs) ; writes fp32 x and bf16 x --------
__global__ __launch_bounds__(384) void add_ln4(
    const float* __restrict__ xin, const float* __restrict__ zs,
    const float* __restrict__ g, const float* __restrict__ be,
    float* __restrict__ xout, u16* __restrict__ xbf)
{
  const long row = blockIdx.x;
  const int d = threadIdx.x;
  const long SL = (long)Bc * Tc * Dc;
  const long o = row * Dc + d;
  float v = xin[o] + zs[o] + zs[SL + o] + zs[2 * SL + o] + zs[3 * SL + o];
  float s = v, s2 = v * v;
#pragma unroll
  for (int off = 32; off > 0; off >>= 1) {
    s  += __shfl_xor(s, off);
    s2 += __shfl_xor(s2, off);
  }
  __shared__ float red[12];
  const int lane = d & 63, wv = d >> 6;
  if (lane == 0) { red[wv] = s; red[6 + wv] = s2; }
  __syncthreads();
  float S = 0.f, S2 = 0.f;
#pragma unroll
  for (int w = 0; w < 6; ++w) { S += red[w]; S2 += red[6 + w]; }
  const float mean = S * (1.0f / Dc);
  const float var  = S2 * (1.0f / Dc) - mean * mean;
  const float rstd = rsqrtf(var + EPSc);
  const float y = (v - mean) * rstd * g[d] + be[d];
  xout[o] = y;
  xbf[o] = f2bf(y);
}

extern "C" void kernel_launch(void* const* d_in, const int* in_sizes, int n_in,
                              void* d_out, int out_size, void* d_ws, size_t ws_size,
                              hipStream_t stream)
{
  const float* tgt     = (const float*)d_in[0];
  const float* memory  = (const float*)d_in[1];
  const float* score_c = (const float*)d_in[2];
  const float* out_c   = (const float*)d_in[3];
  const float* Wq  = (const float*)d_in[4];  const float* bq  = (const float*)d_in[5];
  const float* Wk  = (const float*)d_in[6];  const float* bk  = (const float*)d_in[7];
  const float* Wv  = (const float*)d_in[8];  const float* bv  = (const float*)d_in[9];
  const float* Wkn = (const float*)d_in[10]; const float* bkn = (const float*)d_in[11];
  const float* Wun = (const float*)d_in[12]; const float* bun = (const float*)d_in[13];
  const float* W1  = (const float*)d_in[14]; const float* b1  = (const float*)d_in[15];
  const float* W2  = (const float*)d_in[16]; const float* b2  = (const float*)d_in[17];
  const float* g1  = (const float*)d_in[18]; const float* be1 = (const float*)d_in[19];
  const float* g2  = (const float*)d_in[20]; const float* be2 = (const float*)d_in[21];
  (void)in_sizes; (void)n_in; (void)out_size;

  char* p = (char*)d_ws;
  auto alloc = [&](size_t b) { char* r = p; p += (b + 255) & ~(size_t)255; return r; };

  u16* wk_bf   = (u16*)alloc((size_t)Lc * Dc * DKc * 2);
  u16* wv_bf   = (u16*)alloc((size_t)Lc * Dc * DKc * 2);
  u16* wkn_bf  = (u16*)alloc((size_t)Lc * Dc * Dc * 2);
  u16* w1_bf   = (u16*)alloc((size_t)Lc * FFc * Dc * 2);
  u16* w2_bf   = (u16*)alloc((size_t)Lc * Dc * FFc * 2);
  u16* wqu_bf  = (u16*)alloc((size_t)Lc * 2 * Dc * Dc * 2);  // [l][768][384]
  float* bqu   = (float*)alloc((size_t)Lc * 2 * Dc * 4);
  u16* mem_bf  = (u16*)alloc((size_t)Bc * T1c * DKc * 2);
  u16* outc_bf = (u16*)alloc((size_t)Lc * Bc * TCc * Dc * 2);
  u16* x_bf    = (u16*)alloc((size_t)Bc * Tc * Dc * 2);
  float* xbuf  = (float*)alloc((size_t)Bc * Tc * Dc * 4);
  u16* qunk_bf = (u16*)alloc((size_t)Bc * Tc * 2 * Dc * 2);   // [B*T][768]
  u16* k_all   = (u16*)alloc((size_t)Bc * T1c * Lc * Dc * 2); // [B*T1][1536]
  u16* vT_all  = (u16*)alloc((size_t)Bc * Lc * Dc * T1c * 2); // [b][1536][2048]
  u16* kno_all = (u16*)alloc((size_t)Lc * Bc * TCc * Dc * 2); // [l][B*TC][384]
  u16* s1_bf   = (u16*)alloc((size_t)Bc * Tc * TCc * 2);
  u16* scT_all = (u16*)alloc((size_t)Lc * Bc * T1c * TCc * 2);
  _Float16* att   = (_Float16*)alloc((size_t)Bc * Tc * T1c * 2);
  _Float16* mixed = (_Float16*)alloc((size_t)Bc * Tc * T1c * 2);
  u16* blended = (u16*)alloc((size_t)Bc * Tc * T1c * 2);
  float* zslab = (float*)alloc((size_t)4 * Bc * Tc * Dc * 4);
  float* yslab = (float*)alloc((size_t)4 * Bc * Tc * Dc * 4);
  u16* h_bf    = (u16*)alloc((size_t)Bc * Tc * FFc * 2);

  if ((size_t)(p - (char*)d_ws) > ws_size) return;  // fail loudly (poisoned out)

  auto cvt = [&](const float* s, u16* d, long n) {
    int blocks = (int)((n + 255) / 256); if (blocks > 4096) blocks = 4096;
    cvt_bf16<<<blocks, 256, 0, stream>>>(s, d, n);
  };
  cvt(Wk,  wk_bf,  (long)Lc * Dc * DKc);
  cvt(Wv,  wv_bf,  (long)Lc * Dc * DKc);
  cvt(Wkn, wkn_bf, (long)Lc * Dc * Dc);
  cvt(W1,  w1_bf,  (long)Lc * FFc * Dc);
  cvt(W2,  w2_bf,  (long)Lc * Dc * FFc);
  cvt(memory, mem_bf, (long)Bc * T1c * DKc);
  cvt(out_c, outc_bf, (long)Lc * Bc * TCc * Dc);
  cvt(tgt, x_bf, (long)Bc * Tc * Dc);
  for (int l = 0; l < Lc; ++l) {  // wqu = [Wq[l]; Wun[l]] rows
    cvt(Wq + (long)l * Dc * Dc,  wqu_bf + (long)l * 2 * Dc * Dc, (long)Dc * Dc);
    cvt(Wun + (long)l * Dc * Dc, wqu_bf + (long)l * 2 * Dc * Dc + Dc * Dc, (long)Dc * Dc);
  }
  concat_bias<<<Lc, 2 * Dc, 0, stream>>>(bq, bun, bqu);

  // scT_all: all L*B score_c panels transposed at once
  transpose_cvt<<<dim3(T1c / 32, TCc / 32, Lc * Bc), 256, 0, stream>>>(score_c, scT_all);

  // k_all = memory . Wk_allT + bk_flat   (8192 x 1536, K=256) — all layers
  gemm_bt<1,0,1,0><<<dim3(Lc*Dc/128, Bc*T1c/128, 1), 256, 0, stream>>>(
      mem_bf, wk_bf, k_all, bk, 1.0f, Lc*Dc, DKc, DKc, DKc, 0, 0, 0, 0, 1, 0);
  // vT_all[b] = Wv_all . memory[b]^T + bv(row)   (1536 x 2048, K=256), batch B
  gemm_bt<2,0,1,0><<<dim3(T1c/128, Lc*Dc/128, Bc), 256, 0, stream>>>(
      wv_bf, mem_bf, vT_all, bv, 1.0f, T1c, DKc, DKc, DKc,
      0, (long)T1c*DKc, (long)Lc*Dc*T1c, 0, 1, 0);
  // kno_all[l] = out_c[l] . Wkn[l]^T + bkn[l]   (4096 x 384, K=384), batch L
  gemm_bt<1,0,1,0><<<dim3(Dc/128, Bc*TCc/128, Lc), 256, 0, stream>>>(
      outc_bf, wkn_bf, kno_all, bkn, 1.0f, Dc, Dc, Dc, Dc,
      (long)Bc*TCc*Dc, (long)Dc*Dc, (long)Bc*TCc*Dc, Dc, 1, 0);

  const float scale = 1.0f / sqrtf((float)Dc);
  const long SLAB = (long)Bc * Tc * Dc;

  for (int l = 0; l < Lc; ++l) {
    // qunk = x . [Wq;Wun]^T + [bq;bun]   (4096 x 768, K=384)
    gemm_bt<1,0,1,0><<<dim3(2*Dc/128, Bc*Tc/128, 1), 256, 0, stream>>>(
        x_bf, wqu_bf + (long)l*2*Dc*Dc, qunk_bf, bqu + l*2*Dc,
        1.0f, 2*Dc, Dc, Dc, Dc, 0, 0, 0, 0, 1, 0);
    // att[b] = scale * q[b] . k[b]^T   (1024 x 2048, K=384) -> f16
    gemm_bt<0,0,3,0><<<dim3(T1c/128, Tc/128, Bc), 256, 0, stream>>>(
        qunk_bf, k_all + l*Dc, att, nullptr, scale, T1c, Dc, 2*Dc, Lc*Dc,
        (long)Tc*2*Dc, (long)T1c*Lc*Dc, (long)Tc*T1c, 0, 1, 0);
    // score1[b] = scale * unk[b] . kno[l][b]^T   (1024 x 1024, K=384) bf16
    gemm_bt<0,0,1,0><<<dim3(TCc/128, Tc/128, Bc), 256, 0, stream>>>(
        qunk_bf + Dc, kno_all + (long)l*Bc*TCc*Dc, s1_bf, nullptr, scale,
        TCc, Dc, 2*Dc, Dc, (long)Tc*2*Dc, (long)TCc*Dc, (long)Tc*TCc, 0, 1, 0);
    // mixed[b] = score1[b] . scT[l][b]^T   (1024 x 2048, K=1024) -> f16, swizzled
    gemm_bt<0,0,3,1><<<dim3(T1c/128, Tc/128, Bc), 256, 0, stream>>>(
        s1_bf, scT_all + (long)l*Bc*T1c*TCc, mixed, nullptr, 1.0f,
        T1c, TCc, TCc, TCc, (long)Tc*TCc, (long)T1c*TCc, (long)Tc*T1c, 0, 1, 0);
    // blended = TT*softmax(mixed) + (1-TT)*softmax(att)
    blend_softmax<<<Bc*Tc, 256, 0, stream>>>(att, mixed, blended);
    // z[b] = blended[b] . vT[l][b]^T   (1024 x 384, K=2048), split-K=4 slabs
    gemm_bt<0,0,0,0><<<dim3(Dc/128, Tc/128, Bc*4), 256, 0, stream>>>(
        blended, vT_all + (long)l*Dc*T1c, zslab, nullptr, 1.0f,
        Dc, T1c, T1c, T1c, (long)Tc*T1c, (long)Lc*Dc*T1c, (long)Tc*Dc, 0, 4, SLAB);
    // x = LN(x + sum(zslab))
    add_ln4<<<Bc*Tc, Dc, 0, stream>>>(
        (l == 0) ? tgt : xbuf, zslab, g1 + l*Dc, be1 + l*Dc, xbuf, x_bf);
    // h = relu(x . W1^T + b1)   (4096 x 1536, K=384) bf16
    gemm_bt<1,1,1,0><<<dim3(FFc/128, Bc*Tc/128, 1), 256, 0, stream>>>(
        x_bf, w1_bf + (long)l*FFc*Dc, h_bf, b1 + l*FFc, 1.0f,
        FFc, Dc, Dc, Dc, 0, 0, 0, 0, 1, 0);
    // y2 = h . W2^T + b2   (4096 x 384, K=1536), split-K=4 slabs
    gemm_bt<1,0,0,0><<<dim3(Dc/128, Bc*Tc/128, 4), 256, 0, stream>>>(
        h_bf, w2_bf + (long)l*Dc*FFc, yslab, b2 + l*Dc, 1.0f,
        Dc, FFc, FFc, FFc, 0, 0, 0, 0, 4, SLAB);
    // x = LN(x + sum(yslab)) ; last layer writes d_out
    add_ln4<<<Bc*Tc, Dc, 0, stream>>>(
        xbuf, yslab, g2 + l*Dc, be2 + l*Dc,
        (l == Lc - 1) ? (float*)d_out : xbuf, x_bf);
  }
}